// Round 5
// baseline (190.429 us; speedup 1.0000x reference)
//
#include <hip/hip_runtime.h>

#define NUM_CLS   131072
#define NUM_NODE  70
#define DRUG_NUM  38
#define NSEG      140
#define ROWLEN    70
#define FEA       128
#define MTOT      524288
#define BATCH     8192
#define NB_H      512                 // histogram / scatter blocks (1024 entries each)
#define NCHUNK    32                  // accumulate chunks per segment

typedef __attribute__((ext_vector_type(8))) short bfrag;
typedef __attribute__((ext_vector_type(4))) float f32x4;

__device__ __forceinline__ unsigned short f2bf_rtne(float x) {
  unsigned int u = __float_as_uint(x);
  u = (u + 0x7fffu + ((u >> 16) & 1u)) >> 16;
  return (unsigned short)u;
}
__device__ __forceinline__ float bf2f(unsigned short h) {
  return __uint_as_float((unsigned int)h << 16);
}

// ---------------- P1: per-block segment histogram ----------------
__global__ __launch_bounds__(256) void hist_k(
    const int* __restrict__ he_node, const int* __restrict__ he_edge,
    int* __restrict__ hist_t)        // [NSEG][NB_H]
{
  __shared__ int h[NSEG];
  const int tid = threadIdx.x;
  if (tid < NSEG) h[tid] = 0;
  __syncthreads();
  const int base = blockIdx.x * 1024;
  #pragma unroll
  for (int t = 0; t < 4; ++t) {
    const int e = base + t * 256 + tid;
    const int seg = he_node[e] * 2 + (he_edge[e] >= NUM_CLS);
    atomicAdd(&h[seg], 1);
  }
  __syncthreads();
  if (tid < NSEG) hist_t[tid * NB_H + blockIdx.x] = h[tid];
}

// ---------------- P2a: per-seg exclusive scan over blocks ----------------
__global__ __launch_bounds__(512) void scan_blocks_k(
    const int* __restrict__ hist_t, int* __restrict__ scan_t,
    int* __restrict__ seg_total)
{
  __shared__ int v[NB_H];
  const int s = blockIdx.x, tid = threadIdx.x;
  const int x0 = hist_t[s * NB_H + tid];
  v[tid] = x0;
  __syncthreads();
  for (int off = 1; off < NB_H; off <<= 1) {
    int y = (tid >= off) ? v[tid - off] : 0;
    __syncthreads();
    v[tid] += y;
    __syncthreads();
  }
  scan_t[s * NB_H + tid] = v[tid] - x0;     // exclusive
  if (tid == NB_H - 1) seg_total[s] = v[tid];
}

// ---------------- P2b: segment bases ----------------
__global__ __launch_bounds__(256) void base_k(
    const int* __restrict__ seg_total, int* __restrict__ seg_base,
    float* __restrict__ cnt_f)
{
  __shared__ int tot[NSEG];
  __shared__ int bs[NSEG + 1];
  const int tid = threadIdx.x;
  if (tid < NSEG) tot[tid] = seg_total[tid];
  __syncthreads();
  if (tid == 0) {
    int run = 0;
    for (int s = 0; s < NSEG; ++s) { bs[s] = run; run += tot[s]; }
    bs[NSEG] = run;
  }
  __syncthreads();
  if (tid < NSEG) { seg_base[tid] = bs[tid]; cnt_f[tid] = (float)tot[tid]; }
  if (tid == NSEG) seg_base[NSEG] = bs[NSEG];
}

// ---------------- P3: scatter row-offsets into seg-sorted order ----------------
__global__ __launch_bounds__(256) void scatter_k(
    const int* __restrict__ he_node, const int* __restrict__ he_edge,
    const int* __restrict__ scan_t, const int* __restrict__ seg_base,
    int* __restrict__ sorted_off)
{
  __shared__ int rank[NSEG];
  __shared__ int base[NSEG];
  const int tid = threadIdx.x;
  if (tid < NSEG) {
    rank[tid] = 0;
    base[tid] = seg_base[tid] + scan_t[tid * NB_H + blockIdx.x];
  }
  __syncthreads();
  const int e0 = blockIdx.x * 1024;
  #pragma unroll
  for (int t = 0; t < 4; ++t) {
    const int e = e0 + t * 256 + tid;
    const int node = he_node[e];
    const int edge = he_edge[e];
    const int isdc = (edge >= NUM_CLS);
    const int seg  = node * 2 + isdc;
    const int off  = (isdc ? edge - NUM_CLS : edge) * ROWLEN;
    const int r = atomicAdd(&rank[seg], 1);
    sorted_off[base[seg] + r] = off;
  }
}

// ---------------- P4: register-accumulate rows per (seg, chunk) ----------------
__global__ __launch_bounds__(256) void seg_acc_k(
    const float* __restrict__ dth_cls, const float* __restrict__ dth_dc,
    const int* __restrict__ sorted_off, const int* __restrict__ seg_base,
    float* __restrict__ partial)     // [NSEG][NCHUNK][ROWLEN]
{
  const int s = blockIdx.x;
  const int wid = threadIdx.x >> 6, lane = threadIdx.x & 63;
  const int chunk = blockIdx.y * 4 + wid;
  const int b0 = seg_base[s];
  const int n  = seg_base[s + 1] - b0;
  const int c0 = b0 + (int)(((long long)n * chunk) >> 5);
  const int c1 = b0 + (int)(((long long)n * (chunk + 1)) >> 5);
  const float* __restrict__ T = (s & 1) ? dth_dc : dth_cls;

  float acc[ROWLEN];
  #pragma unroll
  for (int c = 0; c < ROWLEN; ++c) acc[c] = 0.f;

  for (int i = c0 + lane; i < c1; i += 64) {
    const float2* __restrict__ r = (const float2*)(T + sorted_off[i]);
    #pragma unroll
    for (int c = 0; c < 35; ++c) {
      const float2 v = r[c];
      acc[2 * c]     += v.x;
      acc[2 * c + 1] += v.y;
    }
  }

  #pragma unroll
  for (int m = 1; m < 64; m <<= 1) {
    #pragma unroll
    for (int c = 0; c < ROWLEN; ++c) acc[c] += __shfl_xor(acc[c], m, 64);
  }
  if (lane == 0) {
    float* dst = partial + ((size_t)s * NCHUNK + chunk) * ROWLEN;
    #pragma unroll
    for (int c = 0; c < ROWLEN; ++c) dst[c] = acc[c];
  }
}

// ---------------- P5: reduce chunk partials -> rowsum ----------------
__global__ __launch_bounds__(128) void seg_fin_k(
    const float* __restrict__ partial, float* __restrict__ rowsum)
{
  const int s = blockIdx.x, c = threadIdx.x;
  if (c >= ROWLEN) return;
  float v = 0.f;
  #pragma unroll
  for (int k = 0; k < NCHUNK; ++k)
    v += partial[((size_t)s * NCHUNK + k) * ROWLEN + c];
  rowsum[s * ROWLEN + c] = v;
}

// ---------------- K3a: edge_group[s][c] = (rowsum[s] . merge[:,c]) / max(cnt,1) ----
__global__ __launch_bounds__(128) void edge_group_k(
    const float* __restrict__ rowsum, const float* __restrict__ cnt,
    const float* __restrict__ dE, const float* __restrict__ cE,
    float* __restrict__ edge_group)
{
  __shared__ float rs[ROWLEN];
  const int s = blockIdx.x, c = threadIdx.x;
  if (c < ROWLEN) rs[c] = rowsum[s * ROWLEN + c];
  __syncthreads();
  float a = 0.f;
  #pragma unroll
  for (int k = 0; k < DRUG_NUM; ++k) a += rs[k] * dE[k * FEA + c];
  #pragma unroll
  for (int k = DRUG_NUM; k < NUM_NODE; ++k) a += rs[k] * cE[(k - DRUG_NUM) * FEA + c];
  edge_group[s * FEA + c] = a / fmaxf(cnt[s], 1.f);
}

// ---------------- K3b: fc / projections / head-softmax / node_rep ----------------
__global__ __launch_bounds__(128) void node_rep_k(
    const float* __restrict__ edge_group, const float* __restrict__ dE,
    const float* __restrict__ cE, const float* __restrict__ node_proj,
    const float* __restrict__ edge_proj, const float* __restrict__ fc_w,
    const float* __restrict__ fc_b, float* __restrict__ node_rep)
{
  __shared__ float fw[FEA][FEA + 1];
  __shared__ float eg[2][FEA];
  __shared__ float mg[FEA];
  __shared__ float nm[FEA];
  __shared__ float em[2][FEA];
  __shared__ float ef[2][FEA];
  __shared__ float sc[4][2];
  __shared__ float wgt[4][2];

  const int n = blockIdx.x, c = threadIdx.x;
  const int isdrug = (n < DRUG_NUM);
  eg[0][c] = edge_group[(n * 2 + 0) * FEA + c];
  eg[1][c] = edge_group[(n * 2 + 1) * FEA + c];
  mg[c] = isdrug ? dE[n * FEA + c] : cE[(n - DRUG_NUM) * FEA + c];
  for (int r = 0; r < FEA; ++r) fw[r][c] = fc_w[r * FEA + c];
  __syncthreads();

  for (int e = 0; e < 2; ++e) {
    float a = fc_b[c];
    #pragma unroll 8
    for (int k = 0; k < FEA; ++k) a += eg[e][k] * fw[c][k];
    ef[e][c] = fmaxf(a, 0.f);
  }
  {
    const float* P = node_proj + (size_t)(isdrug ? 0 : 1) * FEA * FEA;
    float a = 0.f;
    #pragma unroll 8
    for (int k = 0; k < FEA; ++k) a += mg[k] * P[k * FEA + c];
    nm[c] = a;
  }
  for (int e = 0; e < 2; ++e) {
    const float* P = edge_proj + (size_t)((isdrug ? 0 : 2) + e) * FEA * FEA;
    float a = 0.f;
    #pragma unroll 8
    for (int k = 0; k < FEA; ++k) a += eg[e][k] * P[k * FEA + c];
    em[e][c] = a;
  }
  __syncthreads();

  if (c < 8) {
    const int h = c >> 1, e = c & 1;
    float s = 0.f;
    #pragma unroll
    for (int d = 0; d < 32; ++d) s += nm[h * 32 + d] * em[e][h * 32 + d];
    sc[h][e] = s * 0.17677669529663687f;
  }
  __syncthreads();
  if (c < 2) {
    const int e = c;
    const float mx = fmaxf(fmaxf(sc[0][e], sc[1][e]), fmaxf(sc[2][e], sc[3][e]));
    const float t0 = expf(sc[0][e] - mx), t1 = expf(sc[1][e] - mx);
    const float t2 = expf(sc[2][e] - mx), t3 = expf(sc[3][e] - mx);
    const float inv = 1.f / (t0 + t1 + t2 + t3);
    wgt[0][e] = t0 * inv; wgt[1][e] = t1 * inv;
    wgt[2][e] = t2 * inv; wgt[3][e] = t3 * inv;
  }
  __syncthreads();

  const int h = c >> 5;
  const float v = fmaxf(wgt[h][0] * ef[0][c], 0.f) + fmaxf(wgt[h][1] * ef[1][c], 0.f);
  node_rep[n * FEA + c] = v;
}

// ---------------- cvt: fp32 -> bf16 hi/lo split (RTNE) ----------------
__global__ __launch_bounds__(256) void cvt_split_k(
    const float* __restrict__ src, unsigned short* __restrict__ hi,
    unsigned short* __restrict__ lo, int n)
{
  const int i = blockIdx.x * 256 + threadIdx.x;
  if (i < n) {
    const float v = src[i];
    const unsigned short h = f2bf_rtne(v);
    hi[i] = h;
    lo[i] = f2bf_rtne(v - bf2f(h));
  }
}

// ---------------- K4a: BN'd node_rep per decoder part -> nodeBN[3][70][128] ----
__global__ __launch_bounds__(128) void nodebn_k(
    const float* __restrict__ node_rep,
    const float* __restrict__ gam, const float* __restrict__ bet,
    const float* __restrict__ mean, const float* __restrict__ var,
    unsigned short* __restrict__ nb_hi, unsigned short* __restrict__ nb_lo)
{
  const int n = blockIdx.x, p = blockIdx.y, c = threadIdx.x;
  const int j = p * FEA + c;
  float v = node_rep[n * FEA + c];
  v = (v - mean[j]) * rsqrtf(var[j] + 1e-5f) * gam[j] + bet[j];
  const int o = (p * NUM_NODE + n) * FEA + c;
  const unsigned short h = f2bf_rtne(v);
  nb_hi[o] = h;
  nb_lo[o] = f2bf_rtne(v - bf2f(h));
}

// ---------------- K4b: h1 = lrelu(emb @ w1^T + b1), emb gathered on the fly ----
// split-bf16: acc += ah*bh + ah*bl + al*bh  (~fp32 precision)
__global__ __launch_bounds__(256) void lin1_k(
    const unsigned short* __restrict__ nb_hi, const unsigned short* __restrict__ nb_lo,
    const int* __restrict__ index,
    const unsigned short* __restrict__ w_hi, const unsigned short* __restrict__ w_lo,
    const float* __restrict__ bias,
    unsigned short* __restrict__ h_hi, unsigned short* __restrict__ h_lo)
{
  const int lane = threadIdx.x & 63, wave = threadIdx.x >> 6;
  const int r16 = lane & 15, g = lane >> 4;
  const int row = blockIdx.y * 64 + wave * 16 + r16;
  const int n_base = blockIdx.x * 64;
  const int i0 = index[row * 3 + 0], i1 = index[row * 3 + 1], i2 = index[row * 3 + 2];
  const size_t wrow = (size_t)(n_base + r16) * 384 + g * 8;
  f32x4 acc0 = {0.f, 0.f, 0.f, 0.f}, acc1 = acc0, acc2 = acc0, acc3 = acc0;

  #pragma unroll
  for (int p = 0; p < 3; ++p) {
    const int ip = (p == 0) ? i0 : (p == 1) ? i1 : i2;
    const int abase = (p * NUM_NODE + ip) * FEA + g * 8;
    #pragma unroll
    for (int q = 0; q < 4; ++q) {
      const int k0 = p * 128 + q * 32;
      const bfrag ah = *(const bfrag*)(nb_hi + abase + q * 32);
      const bfrag al = *(const bfrag*)(nb_lo + abase + q * 32);
      const bfrag bh0 = *(const bfrag*)(w_hi + wrow + k0);
      const bfrag bh1 = *(const bfrag*)(w_hi + wrow + (size_t)16 * 384 + k0);
      const bfrag bh2 = *(const bfrag*)(w_hi + wrow + (size_t)32 * 384 + k0);
      const bfrag bh3 = *(const bfrag*)(w_hi + wrow + (size_t)48 * 384 + k0);
      const bfrag bl0 = *(const bfrag*)(w_lo + wrow + k0);
      const bfrag bl1 = *(const bfrag*)(w_lo + wrow + (size_t)16 * 384 + k0);
      const bfrag bl2 = *(const bfrag*)(w_lo + wrow + (size_t)32 * 384 + k0);
      const bfrag bl3 = *(const bfrag*)(w_lo + wrow + (size_t)48 * 384 + k0);
      acc0 = __builtin_amdgcn_mfma_f32_16x16x32_bf16(ah, bh0, acc0, 0, 0, 0);
      acc1 = __builtin_amdgcn_mfma_f32_16x16x32_bf16(ah, bh1, acc1, 0, 0, 0);
      acc2 = __builtin_amdgcn_mfma_f32_16x16x32_bf16(ah, bh2, acc2, 0, 0, 0);
      acc3 = __builtin_amdgcn_mfma_f32_16x16x32_bf16(ah, bh3, acc3, 0, 0, 0);
      acc0 = __builtin_amdgcn_mfma_f32_16x16x32_bf16(ah, bl0, acc0, 0, 0, 0);
      acc1 = __builtin_amdgcn_mfma_f32_16x16x32_bf16(ah, bl1, acc1, 0, 0, 0);
      acc2 = __builtin_amdgcn_mfma_f32_16x16x32_bf16(ah, bl2, acc2, 0, 0, 0);
      acc3 = __builtin_amdgcn_mfma_f32_16x16x32_bf16(ah, bl3, acc3, 0, 0, 0);
      acc0 = __builtin_amdgcn_mfma_f32_16x16x32_bf16(al, bh0, acc0, 0, 0, 0);
      acc1 = __builtin_amdgcn_mfma_f32_16x16x32_bf16(al, bh1, acc1, 0, 0, 0);
      acc2 = __builtin_amdgcn_mfma_f32_16x16x32_bf16(al, bh2, acc2, 0, 0, 0);
      acc3 = __builtin_amdgcn_mfma_f32_16x16x32_bf16(al, bh3, acc3, 0, 0, 0);
    }
  }

  const int mrow = blockIdx.y * 64 + wave * 16 + g * 4;
  f32x4 av[4] = {acc0, acc1, acc2, acc3};
  #pragma unroll
  for (int t = 0; t < 4; ++t) {
    const int col = n_base + 16 * t + r16;
    const float bv = bias[col];
    #pragma unroll
    for (int i = 0; i < 4; ++i) {
      float v = av[t][i] + bv;
      v = v > 0.f ? v : 0.5f * v;
      const size_t o = (size_t)(mrow + i) * 512 + col;
      const unsigned short h = f2bf_rtne(v);
      h_hi[o] = h;
      h_lo[o] = f2bf_rtne(v - bf2f(h));
    }
  }
}

// ---------------- K4c: hout = lrelu(h1 @ w2^T + b2), fp32 out ----------------
__global__ __launch_bounds__(256) void lin2_k(
    const unsigned short* __restrict__ a_hi, const unsigned short* __restrict__ a_lo,
    const unsigned short* __restrict__ w_hi, const unsigned short* __restrict__ w_lo,
    const float* __restrict__ bias, float* __restrict__ C)
{
  const int lane = threadIdx.x & 63, wave = threadIdx.x >> 6;
  const int r16 = lane & 15, g = lane >> 4;
  const int n_base = blockIdx.x * 64;
  const size_t arow = (size_t)(blockIdx.y * 64 + wave * 16 + r16) * 512 + g * 8;
  const size_t wrow = (size_t)(n_base + r16) * 512 + g * 8;
  f32x4 acc0 = {0.f, 0.f, 0.f, 0.f}, acc1 = acc0, acc2 = acc0, acc3 = acc0;

  for (int k0 = 0; k0 < 512; k0 += 32) {
    const bfrag ah = *(const bfrag*)(a_hi + arow + k0);
    const bfrag al = *(const bfrag*)(a_lo + arow + k0);
    const bfrag bh0 = *(const bfrag*)(w_hi + wrow + k0);
    const bfrag bh1 = *(const bfrag*)(w_hi + wrow + (size_t)16 * 512 + k0);
    const bfrag bh2 = *(const bfrag*)(w_hi + wrow + (size_t)32 * 512 + k0);
    const bfrag bh3 = *(const bfrag*)(w_hi + wrow + (size_t)48 * 512 + k0);
    const bfrag bl0 = *(const bfrag*)(w_lo + wrow + k0);
    const bfrag bl1 = *(const bfrag*)(w_lo + wrow + (size_t)16 * 512 + k0);
    const bfrag bl2 = *(const bfrag*)(w_lo + wrow + (size_t)32 * 512 + k0);
    const bfrag bl3 = *(const bfrag*)(w_lo + wrow + (size_t)48 * 512 + k0);
    acc0 = __builtin_amdgcn_mfma_f32_16x16x32_bf16(ah, bh0, acc0, 0, 0, 0);
    acc1 = __builtin_amdgcn_mfma_f32_16x16x32_bf16(ah, bh1, acc1, 0, 0, 0);
    acc2 = __builtin_amdgcn_mfma_f32_16x16x32_bf16(ah, bh2, acc2, 0, 0, 0);
    acc3 = __builtin_amdgcn_mfma_f32_16x16x32_bf16(ah, bh3, acc3, 0, 0, 0);
    acc0 = __builtin_amdgcn_mfma_f32_16x16x32_bf16(ah, bl0, acc0, 0, 0, 0);
    acc1 = __builtin_amdgcn_mfma_f32_16x16x32_bf16(ah, bl1, acc1, 0, 0, 0);
    acc2 = __builtin_amdgcn_mfma_f32_16x16x32_bf16(ah, bl2, acc2, 0, 0, 0);
    acc3 = __builtin_amdgcn_mfma_f32_16x16x32_bf16(ah, bl3, acc3, 0, 0, 0);
    acc0 = __builtin_amdgcn_mfma_f32_16x16x32_bf16(al, bh0, acc0, 0, 0, 0);
    acc1 = __builtin_amdgcn_mfma_f32_16x16x32_bf16(al, bh1, acc1, 0, 0, 0);
    acc2 = __builtin_amdgcn_mfma_f32_16x16x32_bf16(al, bh2, acc2, 0, 0, 0);
    acc3 = __builtin_amdgcn_mfma_f32_16x16x32_bf16(al, bh3, acc3, 0, 0, 0);
  }

  const int mrow = blockIdx.y * 64 + wave * 16 + g * 4;
  f32x4 av[4] = {acc0, acc1, acc2, acc3};
  #pragma unroll
  for (int t = 0; t < 4; ++t) {
    const int col = n_base + 16 * t + r16;
    const float bv = bias[col];
    #pragma unroll
    for (int i = 0; i < 4; ++i) {
      float v = av[t][i] + bv;
      v = v > 0.f ? v : 0.5f * v;
      C[(size_t)(mrow + i) * 256 + col] = v;
    }
  }
}

// ---------------- K4d: out0 = sigmoid(h @ w3 + b3) ----------------
__global__ __launch_bounds__(256) void lin3_k(
    const float* __restrict__ H, const float* __restrict__ w3,
    const float* __restrict__ b3, float* __restrict__ out)
{
  const int row = blockIdx.x * 4 + (threadIdx.x >> 6);
  const int lane = threadIdx.x & 63;
  const float4 h = *(const float4*)(H + (size_t)row * 256 + lane * 4);
  const float4 w = *(const float4*)(w3 + lane * 4);
  float v = h.x * w.x + h.y * w.y + h.z * w.z + h.w * w.w;
  #pragma unroll
  for (int off = 32; off; off >>= 1) v += __shfl_down(v, off);
  if (lane == 0) out[row] = 1.f / (1.f + expf(-(v + b3[0])));
}

extern "C" void kernel_launch(void* const* d_in, const int* in_sizes, int n_in,
                              void* d_out, int out_size, void* d_ws, size_t ws_size,
                              hipStream_t stream) {
  const float* dth_cls  = (const float*)d_in[2];
  const float* dth_dc   = (const float*)d_in[3];
  const int*   he_node  = (const int*)d_in[4];
  const int*   he_edge  = (const int*)d_in[5];
  const int*   index    = (const int*)d_in[7];
  const float* dE       = (const float*)d_in[8];
  const float* cE       = (const float*)d_in[9];
  const float* node_proj= (const float*)d_in[10];
  const float* edge_proj= (const float*)d_in[11];
  const float* fc_w     = (const float*)d_in[12];
  const float* fc_b     = (const float*)d_in[13];
  const float* bn_g     = (const float*)d_in[14];
  const float* bn_b     = (const float*)d_in[15];
  const float* bn_m     = (const float*)d_in[16];
  const float* bn_v     = (const float*)d_in[17];
  const float* w1       = (const float*)d_in[18];
  const float* b1       = (const float*)d_in[19];
  const float* w2       = (const float*)d_in[20];
  const float* b2       = (const float*)d_in[21];
  const float* w3       = (const float*)d_in[22];
  const float* b3       = (const float*)d_in[23];

  float* out0 = (float*)d_out;
  float* hout = out0 + BATCH;                      // [8192,256] fp32, 2nd output

  float* ws = (float*)d_ws;
  float*          rowsum    = ws + 0;                          // -> 9800
  float*          cnt_f     = ws + 9856;                       // -> 9996
  float*          edge_group= ws + 10048;                      // -> 27968
  float*          node_rep  = ws + 28032;                      // -> 36992
  unsigned short* nb_hi     = (unsigned short*)(ws + 37056);   // 26880 bf16
  unsigned short* nb_lo     = (unsigned short*)(ws + 50560);   // 26880 bf16
  unsigned short* w1_hi     = (unsigned short*)(ws + 64000);   // 196608 bf16
  unsigned short* w1_lo     = (unsigned short*)(ws + 162304);
  unsigned short* w2_hi     = (unsigned short*)(ws + 260608);  // 131072 bf16
  unsigned short* w2_lo     = (unsigned short*)(ws + 326144);
  unsigned short* h1_hi     = (unsigned short*)(ws + 391744);  // 8192*512 bf16 -> +2097152 fl
  unsigned short* h1_lo     = (unsigned short*)(ws + 2488960); // -> end 4586112 fl (18.3 MB)
  // seg scratch aliased into h1 span (fully consumed before lin1 writes h1):
  int*            sorted_off= (int*)(ws + 391744);             // 524288 -> 916032
  int*            hist_t    = (int*)(ws + 916032);             // 71680
  int*            scan_t    = (int*)(ws + 987712);             // 71680
  int*            seg_total = (int*)(ws + 1059392);            // 140
  int*            seg_base  = (int*)(ws + 1059532);            // 141
  float*          partial   = ws + 1059680;                    // 313600 -> 1373280

  // weight split conversions (independent of everything else)
  cvt_split_k<<<(512 * 384 + 255) / 256, 256, 0, stream>>>(w1, w1_hi, w1_lo, 512 * 384);
  cvt_split_k<<<(256 * 512 + 255) / 256, 256, 0, stream>>>(w2, w2_hi, w2_lo, 256 * 512);

  // segment-mean pipeline
  hist_k<<<NB_H, 256, 0, stream>>>(he_node, he_edge, hist_t);
  scan_blocks_k<<<NSEG, NB_H, 0, stream>>>(hist_t, scan_t, seg_total);
  base_k<<<1, 256, 0, stream>>>(seg_total, seg_base, cnt_f);
  scatter_k<<<NB_H, 256, 0, stream>>>(he_node, he_edge, scan_t, seg_base, sorted_off);
  seg_acc_k<<<dim3(NSEG, NCHUNK / 4), 256, 0, stream>>>(dth_cls, dth_dc, sorted_off,
                                                        seg_base, partial);
  seg_fin_k<<<NSEG, 128, 0, stream>>>(partial, rowsum);
  edge_group_k<<<NSEG, 128, 0, stream>>>(rowsum, cnt_f, dE, cE, edge_group);
  node_rep_k<<<NUM_NODE, 128, 0, stream>>>(edge_group, dE, cE, node_proj, edge_proj,
                                           fc_w, fc_b, node_rep);

  // decoder: split-bf16 MFMA, emb gathered on the fly
  nodebn_k<<<dim3(NUM_NODE, 3), 128, 0, stream>>>(node_rep, bn_g, bn_b, bn_m, bn_v,
                                                  nb_hi, nb_lo);
  lin1_k<<<dim3(512 / 64, BATCH / 64), 256, 0, stream>>>(nb_hi, nb_lo, index,
                                                         w1_hi, w1_lo, b1, h1_hi, h1_lo);
  lin2_k<<<dim3(256 / 64, BATCH / 64), 256, 0, stream>>>(h1_hi, h1_lo, w2_hi, w2_lo,
                                                         b2, hout);
  lin3_k<<<BATCH / 4, 256, 0, stream>>>(hout, w3, b3, out0);
}

// Round 6
// 160.484 us; speedup vs baseline: 1.1866x; 1.1866x over previous
//
#include <hip/hip_runtime.h>

#define NUM_CLS   131072
#define NUM_NODE  70
#define DRUG_NUM  38
#define NSEG      140
#define ROWLEN    70
#define FEA       128
#define MTOT      524288
#define BATCH     8192
#define NB_H      512                 // histogram / scatter blocks (1024 entries each)
#define NCHUNK    32                  // accumulate chunks per segment

typedef __attribute__((ext_vector_type(8))) short bfrag;
typedef __attribute__((ext_vector_type(4))) float f32x4;

__device__ __forceinline__ unsigned short f2bf_rtne(float x) {
  unsigned int u = __float_as_uint(x);
  u = (u + 0x7fffu + ((u >> 16) & 1u)) >> 16;
  return (unsigned short)u;
}
__device__ __forceinline__ float bf2f(unsigned short h) {
  return __uint_as_float((unsigned int)h << 16);
}
#define MFMA16(a, b, c) __builtin_amdgcn_mfma_f32_16x16x32_bf16((a), (b), (c), 0, 0, 0)

// ---------------- P1: per-block segment histogram ----------------
__global__ __launch_bounds__(256) void hist_k(
    const int* __restrict__ he_node, const int* __restrict__ he_edge,
    int* __restrict__ hist_t)        // [NSEG][NB_H]
{
  __shared__ int h[NSEG];
  const int tid = threadIdx.x;
  if (tid < NSEG) h[tid] = 0;
  __syncthreads();
  const int base = blockIdx.x * 1024;
  #pragma unroll
  for (int t = 0; t < 4; ++t) {
    const int e = base + t * 256 + tid;
    const int seg = he_node[e] * 2 + (he_edge[e] >= NUM_CLS);
    atomicAdd(&h[seg], 1);
  }
  __syncthreads();
  if (tid < NSEG) hist_t[tid * NB_H + blockIdx.x] = h[tid];
}

// ---------------- P2a: per-seg exclusive scan over blocks ----------------
__global__ __launch_bounds__(512) void scan_blocks_k(
    const int* __restrict__ hist_t, int* __restrict__ scan_t,
    int* __restrict__ seg_total)
{
  __shared__ int v[NB_H];
  const int s = blockIdx.x, tid = threadIdx.x;
  const int x0 = hist_t[s * NB_H + tid];
  v[tid] = x0;
  __syncthreads();
  for (int off = 1; off < NB_H; off <<= 1) {
    int y = (tid >= off) ? v[tid - off] : 0;
    __syncthreads();
    v[tid] += y;
    __syncthreads();
  }
  scan_t[s * NB_H + tid] = v[tid] - x0;     // exclusive
  if (tid == NB_H - 1) seg_total[s] = v[tid];
}

// ---------------- P2b: segment bases ----------------
__global__ __launch_bounds__(256) void base_k(
    const int* __restrict__ seg_total, int* __restrict__ seg_base,
    float* __restrict__ cnt_f)
{
  __shared__ int tot[NSEG];
  __shared__ int bs[NSEG + 1];
  const int tid = threadIdx.x;
  if (tid < NSEG) tot[tid] = seg_total[tid];
  __syncthreads();
  if (tid == 0) {
    int run = 0;
    for (int s = 0; s < NSEG; ++s) { bs[s] = run; run += tot[s]; }
    bs[NSEG] = run;
  }
  __syncthreads();
  if (tid < NSEG) { seg_base[tid] = bs[tid]; cnt_f[tid] = (float)tot[tid]; }
  if (tid == NSEG) seg_base[NSEG] = bs[NSEG];
}

// ---------------- P3: scatter row-offsets into seg-sorted order ----------------
__global__ __launch_bounds__(256) void scatter_k(
    const int* __restrict__ he_node, const int* __restrict__ he_edge,
    const int* __restrict__ scan_t, const int* __restrict__ seg_base,
    int* __restrict__ sorted_off)
{
  __shared__ int rank[NSEG];
  __shared__ int base[NSEG];
  const int tid = threadIdx.x;
  if (tid < NSEG) {
    rank[tid] = 0;
    base[tid] = seg_base[tid] + scan_t[tid * NB_H + blockIdx.x];
  }
  __syncthreads();
  const int e0 = blockIdx.x * 1024;
  #pragma unroll
  for (int t = 0; t < 4; ++t) {
    const int e = e0 + t * 256 + tid;
    const int node = he_node[e];
    const int edge = he_edge[e];
    const int isdc = (edge >= NUM_CLS);
    const int seg  = node * 2 + isdc;
    const int off  = (isdc ? edge - NUM_CLS : edge) * ROWLEN;
    const int r = atomicAdd(&rank[seg], 1);
    sorted_off[base[seg] + r] = off;
  }
}

// ---------------- P4: register-accumulate rows per (seg, chunk) ----------------
__global__ __launch_bounds__(256) void seg_acc_k(
    const float* __restrict__ dth_cls, const float* __restrict__ dth_dc,
    const int* __restrict__ sorted_off, const int* __restrict__ seg_base,
    float* __restrict__ partial)     // [NSEG][NCHUNK][ROWLEN]
{
  const int s = blockIdx.x;
  const int wid = threadIdx.x >> 6, lane = threadIdx.x & 63;
  const int chunk = blockIdx.y * 4 + wid;
  const int b0 = seg_base[s];
  const int n  = seg_base[s + 1] - b0;
  const int c0 = b0 + (int)(((long long)n * chunk) >> 5);
  const int c1 = b0 + (int)(((long long)n * (chunk + 1)) >> 5);
  const float* __restrict__ T = (s & 1) ? dth_dc : dth_cls;

  float acc[ROWLEN];
  #pragma unroll
  for (int c = 0; c < ROWLEN; ++c) acc[c] = 0.f;

  for (int i = c0 + lane; i < c1; i += 64) {
    const float2* __restrict__ r = (const float2*)(T + sorted_off[i]);
    #pragma unroll
    for (int c = 0; c < 35; ++c) {
      const float2 v = r[c];
      acc[2 * c]     += v.x;
      acc[2 * c + 1] += v.y;
    }
  }

  #pragma unroll
  for (int m = 1; m < 64; m <<= 1) {
    #pragma unroll
    for (int c = 0; c < ROWLEN; ++c) acc[c] += __shfl_xor(acc[c], m, 64);
  }
  if (lane == 0) {
    float* dst = partial + ((size_t)s * NCHUNK + chunk) * ROWLEN;
    #pragma unroll
    for (int c = 0; c < ROWLEN; ++c) dst[c] = acc[c];
  }
}

// ---------------- P5: reduce chunk partials -> rowsum ----------------
__global__ __launch_bounds__(128) void seg_fin_k(
    const float* __restrict__ partial, float* __restrict__ rowsum)
{
  const int s = blockIdx.x, c = threadIdx.x;
  if (c >= ROWLEN) return;
  float v = 0.f;
  #pragma unroll
  for (int k = 0; k < NCHUNK; ++k)
    v += partial[((size_t)s * NCHUNK + k) * ROWLEN + c];
  rowsum[s * ROWLEN + c] = v;
}

// ---------------- K3a: edge_group[s][c] = (rowsum[s] . merge[:,c]) / max(cnt,1) ----
__global__ __launch_bounds__(128) void edge_group_k(
    const float* __restrict__ rowsum, const float* __restrict__ cnt,
    const float* __restrict__ dE, const float* __restrict__ cE,
    float* __restrict__ edge_group)
{
  __shared__ float rs[ROWLEN];
  const int s = blockIdx.x, c = threadIdx.x;
  if (c < ROWLEN) rs[c] = rowsum[s * ROWLEN + c];
  __syncthreads();
  float a = 0.f;
  #pragma unroll
  for (int k = 0; k < DRUG_NUM; ++k) a += rs[k] * dE[k * FEA + c];
  #pragma unroll
  for (int k = DRUG_NUM; k < NUM_NODE; ++k) a += rs[k] * cE[(k - DRUG_NUM) * FEA + c];
  edge_group[s * FEA + c] = a / fmaxf(cnt[s], 1.f);
}

// ---------------- K3b: fc / projections / head-softmax / node_rep ----------------
__global__ __launch_bounds__(128) void node_rep_k(
    const float* __restrict__ edge_group, const float* __restrict__ dE,
    const float* __restrict__ cE, const float* __restrict__ node_proj,
    const float* __restrict__ edge_proj, const float* __restrict__ fc_w,
    const float* __restrict__ fc_b, float* __restrict__ node_rep)
{
  __shared__ float fw[FEA][FEA + 1];
  __shared__ float eg[2][FEA];
  __shared__ float mg[FEA];
  __shared__ float nm[FEA];
  __shared__ float em[2][FEA];
  __shared__ float ef[2][FEA];
  __shared__ float sc[4][2];
  __shared__ float wgt[4][2];

  const int n = blockIdx.x, c = threadIdx.x;
  const int isdrug = (n < DRUG_NUM);
  eg[0][c] = edge_group[(n * 2 + 0) * FEA + c];
  eg[1][c] = edge_group[(n * 2 + 1) * FEA + c];
  mg[c] = isdrug ? dE[n * FEA + c] : cE[(n - DRUG_NUM) * FEA + c];
  for (int r = 0; r < FEA; ++r) fw[r][c] = fc_w[r * FEA + c];
  __syncthreads();

  for (int e = 0; e < 2; ++e) {
    float a = fc_b[c];
    #pragma unroll 8
    for (int k = 0; k < FEA; ++k) a += eg[e][k] * fw[c][k];
    ef[e][c] = fmaxf(a, 0.f);
  }
  {
    const float* P = node_proj + (size_t)(isdrug ? 0 : 1) * FEA * FEA;
    float a = 0.f;
    #pragma unroll 8
    for (int k = 0; k < FEA; ++k) a += mg[k] * P[k * FEA + c];
    nm[c] = a;
  }
  for (int e = 0; e < 2; ++e) {
    const float* P = edge_proj + (size_t)((isdrug ? 0 : 2) + e) * FEA * FEA;
    float a = 0.f;
    #pragma unroll 8
    for (int k = 0; k < FEA; ++k) a += eg[e][k] * P[k * FEA + c];
    em[e][c] = a;
  }
  __syncthreads();

  if (c < 8) {
    const int h = c >> 1, e = c & 1;
    float s = 0.f;
    #pragma unroll
    for (int d = 0; d < 32; ++d) s += nm[h * 32 + d] * em[e][h * 32 + d];
    sc[h][e] = s * 0.17677669529663687f;
  }
  __syncthreads();
  if (c < 2) {
    const int e = c;
    const float mx = fmaxf(fmaxf(sc[0][e], sc[1][e]), fmaxf(sc[2][e], sc[3][e]));
    const float t0 = expf(sc[0][e] - mx), t1 = expf(sc[1][e] - mx);
    const float t2 = expf(sc[2][e] - mx), t3 = expf(sc[3][e] - mx);
    const float inv = 1.f / (t0 + t1 + t2 + t3);
    wgt[0][e] = t0 * inv; wgt[1][e] = t1 * inv;
    wgt[2][e] = t2 * inv; wgt[3][e] = t3 * inv;
  }
  __syncthreads();

  const int h = c >> 5;
  const float v = fmaxf(wgt[h][0] * ef[0][c], 0.f) + fmaxf(wgt[h][1] * ef[1][c], 0.f);
  node_rep[n * FEA + c] = v;
}

// ---------------- cvt: fp32 -> bf16 hi/lo split (RTNE) ----------------
__global__ __launch_bounds__(256) void cvt_split_k(
    const float* __restrict__ src, unsigned short* __restrict__ hi,
    unsigned short* __restrict__ lo, int n)
{
  const int i = blockIdx.x * 256 + threadIdx.x;
  if (i < n) {
    const float v = src[i];
    const unsigned short h = f2bf_rtne(v);
    hi[i] = h;
    lo[i] = f2bf_rtne(v - bf2f(h));
  }
}

// ---------------- K4a: BN'd node_rep per decoder part -> nodeBN[3][70][128] ----
__global__ __launch_bounds__(128) void nodebn_k(
    const float* __restrict__ node_rep,
    const float* __restrict__ gam, const float* __restrict__ bet,
    const float* __restrict__ mean, const float* __restrict__ var,
    unsigned short* __restrict__ nb_hi, unsigned short* __restrict__ nb_lo)
{
  const int n = blockIdx.x, p = blockIdx.y, c = threadIdx.x;
  const int j = p * FEA + c;
  float v = node_rep[n * FEA + c];
  v = (v - mean[j]) * rsqrtf(var[j] + 1e-5f) * gam[j] + bet[j];
  const int o = (p * NUM_NODE + n) * FEA + c;
  const unsigned short h = f2bf_rtne(v);
  nb_hi[o] = h;
  nb_lo[o] = f2bf_rtne(v - bf2f(h));
}

// ---------------- K4b: h1 = lrelu(emb @ w1^T + b1), split-bf16 MFMA ----
// Block 128x64, 4 waves (2x2); wave tile 64 rows x 32 cols = 8 acc fragments.
// AI = 24 MFMA / 12 loads per k-step; 8 independent MFMA chains for latency.
__global__ __launch_bounds__(256) void lin1_k(
    const unsigned short* __restrict__ nb_hi, const unsigned short* __restrict__ nb_lo,
    const int* __restrict__ index,
    const unsigned short* __restrict__ w_hi, const unsigned short* __restrict__ w_lo,
    const float* __restrict__ bias,
    unsigned short* __restrict__ h_hi, unsigned short* __restrict__ h_lo)
{
  const int lane = threadIdx.x & 63, wave = threadIdx.x >> 6;
  const int r16 = lane & 15, g = lane >> 4;
  const int wr = wave >> 1, wc = wave & 1;
  const int rowbase = blockIdx.y * 128 + wr * 64;
  const int colbase = blockIdx.x * 64 + wc * 32;

  int idx[4][3];                       // 4 row-frags x 3 parts (all static idx)
  #pragma unroll
  for (int t = 0; t < 4; ++t) {
    const int r = rowbase + t * 16 + r16;
    idx[t][0] = index[r * 3 + 0];
    idx[t][1] = index[r * 3 + 1];
    idx[t][2] = index[r * 3 + 2];
  }

  f32x4 acc[4][2];
  #pragma unroll
  for (int t = 0; t < 4; ++t) {
    acc[t][0] = (f32x4){0.f, 0.f, 0.f, 0.f};
    acc[t][1] = (f32x4){0.f, 0.f, 0.f, 0.f};
  }

  const size_t wrow0 = (size_t)(colbase + r16) * 384 + g * 8;
  const size_t wrow1 = (size_t)(colbase + 16 + r16) * 384 + g * 8;

  #pragma unroll
  for (int p = 0; p < 3; ++p) {
    #pragma unroll
    for (int q = 0; q < 4; ++q) {
      const int k0 = p * 128 + q * 32;
      bfrag ah[4], al[4];
      #pragma unroll
      for (int t = 0; t < 4; ++t) {
        const int abase = (p * NUM_NODE + idx[t][p]) * FEA + q * 32 + g * 8;
        ah[t] = *(const bfrag*)(nb_hi + abase);
        al[t] = *(const bfrag*)(nb_lo + abase);
      }
      const bfrag bh0 = *(const bfrag*)(w_hi + wrow0 + k0);
      const bfrag bh1 = *(const bfrag*)(w_hi + wrow1 + k0);
      const bfrag bl0 = *(const bfrag*)(w_lo + wrow0 + k0);
      const bfrag bl1 = *(const bfrag*)(w_lo + wrow1 + k0);
      #pragma unroll
      for (int t = 0; t < 4; ++t) {
        acc[t][0] = MFMA16(ah[t], bh0, acc[t][0]);
        acc[t][0] = MFMA16(ah[t], bl0, acc[t][0]);
        acc[t][0] = MFMA16(al[t], bh0, acc[t][0]);
        acc[t][1] = MFMA16(ah[t], bh1, acc[t][1]);
        acc[t][1] = MFMA16(ah[t], bl1, acc[t][1]);
        acc[t][1] = MFMA16(al[t], bh1, acc[t][1]);
      }
    }
  }

  #pragma unroll
  for (int t = 0; t < 4; ++t) {
    #pragma unroll
    for (int u = 0; u < 2; ++u) {
      const int col = colbase + u * 16 + r16;
      const float bv = bias[col];
      #pragma unroll
      for (int i = 0; i < 4; ++i) {
        float v = acc[t][u][i] + bv;
        v = v > 0.f ? v : 0.5f * v;
        const size_t o = (size_t)(rowbase + t * 16 + g * 4 + i) * 512 + col;
        const unsigned short h = f2bf_rtne(v);
        h_hi[o] = h;
        h_lo[o] = f2bf_rtne(v - bf2f(h));
      }
    }
  }
}

// ---------------- K4c: hout = lrelu(h1 @ w2^T + b2), fp32 out ----------------
// Block 128x64, 8 waves (4x2, 512 thr); wave tile 32x32 = 4 acc fragments.
__global__ __launch_bounds__(512) void lin2_k(
    const unsigned short* __restrict__ a_hi, const unsigned short* __restrict__ a_lo,
    const unsigned short* __restrict__ w_hi, const unsigned short* __restrict__ w_lo,
    const float* __restrict__ bias, float* __restrict__ C)
{
  const int lane = threadIdx.x & 63, wave = threadIdx.x >> 6;
  const int r16 = lane & 15, g = lane >> 4;
  const int wr = wave >> 1, wc = wave & 1;
  const int rowbase = blockIdx.y * 128 + wr * 32;
  const int colbase = blockIdx.x * 64 + wc * 32;

  const size_t arow0 = (size_t)(rowbase + r16) * 512 + g * 8;
  const size_t arow1 = (size_t)(rowbase + 16 + r16) * 512 + g * 8;
  const size_t wrow0 = (size_t)(colbase + r16) * 512 + g * 8;
  const size_t wrow1 = (size_t)(colbase + 16 + r16) * 512 + g * 8;

  f32x4 acc00 = {0.f, 0.f, 0.f, 0.f}, acc01 = acc00, acc10 = acc00, acc11 = acc00;

  #pragma unroll 4
  for (int k0 = 0; k0 < 512; k0 += 32) {
    const bfrag ah0 = *(const bfrag*)(a_hi + arow0 + k0);
    const bfrag ah1 = *(const bfrag*)(a_hi + arow1 + k0);
    const bfrag al0 = *(const bfrag*)(a_lo + arow0 + k0);
    const bfrag al1 = *(const bfrag*)(a_lo + arow1 + k0);
    const bfrag bh0 = *(const bfrag*)(w_hi + wrow0 + k0);
    const bfrag bh1 = *(const bfrag*)(w_hi + wrow1 + k0);
    const bfrag bl0 = *(const bfrag*)(w_lo + wrow0 + k0);
    const bfrag bl1 = *(const bfrag*)(w_lo + wrow1 + k0);
    acc00 = MFMA16(ah0, bh0, acc00); acc00 = MFMA16(ah0, bl0, acc00); acc00 = MFMA16(al0, bh0, acc00);
    acc01 = MFMA16(ah0, bh1, acc01); acc01 = MFMA16(ah0, bl1, acc01); acc01 = MFMA16(al0, bh1, acc01);
    acc10 = MFMA16(ah1, bh0, acc10); acc10 = MFMA16(ah1, bl0, acc10); acc10 = MFMA16(al1, bh0, acc10);
    acc11 = MFMA16(ah1, bh1, acc11); acc11 = MFMA16(ah1, bl1, acc11); acc11 = MFMA16(al1, bh1, acc11);
  }

  f32x4 av[2][2] = {{acc00, acc01}, {acc10, acc11}};
  #pragma unroll
  for (int t = 0; t < 2; ++t) {
    #pragma unroll
    for (int u = 0; u < 2; ++u) {
      const int col = colbase + u * 16 + r16;
      const float bv = bias[col];
      #pragma unroll
      for (int i = 0; i < 4; ++i) {
        float v = av[t][u][i] + bv;
        v = v > 0.f ? v : 0.5f * v;
        C[(size_t)(rowbase + t * 16 + g * 4 + i) * 256 + col] = v;
      }
    }
  }
}

// ---------------- K4d: out0 = sigmoid(h @ w3 + b3) ----------------
__global__ __launch_bounds__(256) void lin3_k(
    const float* __restrict__ H, const float* __restrict__ w3,
    const float* __restrict__ b3, float* __restrict__ out)
{
  const int row = blockIdx.x * 4 + (threadIdx.x >> 6);
  const int lane = threadIdx.x & 63;
  const float4 h = *(const float4*)(H + (size_t)row * 256 + lane * 4);
  const float4 w = *(const float4*)(w3 + lane * 4);
  float v = h.x * w.x + h.y * w.y + h.z * w.z + h.w * w.w;
  #pragma unroll
  for (int off = 32; off; off >>= 1) v += __shfl_down(v, off);
  if (lane == 0) out[row] = 1.f / (1.f + expf(-(v + b3[0])));
}

extern "C" void kernel_launch(void* const* d_in, const int* in_sizes, int n_in,
                              void* d_out, int out_size, void* d_ws, size_t ws_size,
                              hipStream_t stream) {
  const float* dth_cls  = (const float*)d_in[2];
  const float* dth_dc   = (const float*)d_in[3];
  const int*   he_node  = (const int*)d_in[4];
  const int*   he_edge  = (const int*)d_in[5];
  const int*   index    = (const int*)d_in[7];
  const float* dE       = (const float*)d_in[8];
  const float* cE       = (const float*)d_in[9];
  const float* node_proj= (const float*)d_in[10];
  const float* edge_proj= (const float*)d_in[11];
  const float* fc_w     = (const float*)d_in[12];
  const float* fc_b     = (const float*)d_in[13];
  const float* bn_g     = (const float*)d_in[14];
  const float* bn_b     = (const float*)d_in[15];
  const float* bn_m     = (const float*)d_in[16];
  const float* bn_v     = (const float*)d_in[17];
  const float* w1       = (const float*)d_in[18];
  const float* b1       = (const float*)d_in[19];
  const float* w2       = (const float*)d_in[20];
  const float* b2       = (const float*)d_in[21];
  const float* w3       = (const float*)d_in[22];
  const float* b3       = (const float*)d_in[23];

  float* out0 = (float*)d_out;
  float* hout = out0 + BATCH;                      // [8192,256] fp32, 2nd output

  float* ws = (float*)d_ws;
  float*          rowsum    = ws + 0;                          // -> 9800
  float*          cnt_f     = ws + 9856;                       // -> 9996
  float*          edge_group= ws + 10048;                      // -> 27968
  float*          node_rep  = ws + 28032;                      // -> 36992
  unsigned short* nb_hi     = (unsigned short*)(ws + 37056);   // 26880 bf16
  unsigned short* nb_lo     = (unsigned short*)(ws + 50560);   // 26880 bf16
  unsigned short* w1_hi     = (unsigned short*)(ws + 64000);   // 196608 bf16
  unsigned short* w1_lo     = (unsigned short*)(ws + 162304);
  unsigned short* w2_hi     = (unsigned short*)(ws + 260608);  // 131072 bf16
  unsigned short* w2_lo     = (unsigned short*)(ws + 326144);
  unsigned short* h1_hi     = (unsigned short*)(ws + 391744);  // 8192*512 bf16 -> +2097152 fl
  unsigned short* h1_lo     = (unsigned short*)(ws + 2488960); // -> end 4586112 fl (18.3 MB)
  // seg scratch aliased into h1 span (fully consumed before lin1 writes h1):
  int*            sorted_off= (int*)(ws + 391744);             // 524288 -> 916032
  int*            hist_t    = (int*)(ws + 916032);             // 71680
  int*            scan_t    = (int*)(ws + 987712);             // 71680
  int*            seg_total = (int*)(ws + 1059392);            // 140
  int*            seg_base  = (int*)(ws + 1059532);            // 141
  float*          partial   = ws + 1059680;                    // 313600 -> 1373280

  // weight split conversions (independent of everything else)
  cvt_split_k<<<(512 * 384 + 255) / 256, 256, 0, stream>>>(w1, w1_hi, w1_lo, 512 * 384);
  cvt_split_k<<<(256 * 512 + 255) / 256, 256, 0, stream>>>(w2, w2_hi, w2_lo, 256 * 512);

  // segment-mean pipeline
  hist_k<<<NB_H, 256, 0, stream>>>(he_node, he_edge, hist_t);
  scan_blocks_k<<<NSEG, NB_H, 0, stream>>>(hist_t, scan_t, seg_total);
  base_k<<<1, 256, 0, stream>>>(seg_total, seg_base, cnt_f);
  scatter_k<<<NB_H, 256, 0, stream>>>(he_node, he_edge, scan_t, seg_base, sorted_off);
  seg_acc_k<<<dim3(NSEG, NCHUNK / 4), 256, 0, stream>>>(dth_cls, dth_dc, sorted_off,
                                                        seg_base, partial);
  seg_fin_k<<<NSEG, 128, 0, stream>>>(partial, rowsum);
  edge_group_k<<<NSEG, 128, 0, stream>>>(rowsum, cnt_f, dE, cE, edge_group);
  node_rep_k<<<NUM_NODE, 128, 0, stream>>>(edge_group, dE, cE, node_proj, edge_proj,
                                           fc_w, fc_b, node_rep);

  // decoder: split-bf16 MFMA, emb gathered on the fly
  nodebn_k<<<dim3(NUM_NODE, 3), 128, 0, stream>>>(node_rep, bn_g, bn_b, bn_m, bn_v,
                                                  nb_hi, nb_lo);
  lin1_k<<<dim3(512 / 64, BATCH / 128), 256, 0, stream>>>(nb_hi, nb_lo, index,
                                                          w1_hi, w1_lo, b1, h1_hi, h1_lo);
  lin2_k<<<dim3(256 / 64, BATCH / 128), 512, 0, stream>>>(h1_hi, h1_lo, w2_hi, w2_lo,
                                                          b2, hout);
  lin3_k<<<BATCH / 4, 256, 0, stream>>>(hout, w3, b3, out0);
}

// Round 7
// 154.143 us; speedup vs baseline: 1.2354x; 1.0411x over previous
//
#include <hip/hip_runtime.h>

#define NUM_CLS   131072
#define NUM_NODE  70
#define DRUG_NUM  38
#define NSEG      140
#define ROWLEN    70
#define FEA       128
#define MTOT      524288
#define BATCH     8192
#define NB_H      512                 // histogram / scatter blocks (1024 entries each)
#define NCHUNK    32                  // accumulate chunks per segment

typedef __attribute__((ext_vector_type(8))) short bfrag;
typedef __attribute__((ext_vector_type(4))) float f32x4;

__device__ __forceinline__ unsigned short f2bf_rtne(float x) {
  unsigned int u = __float_as_uint(x);
  u = (u + 0x7fffu + ((u >> 16) & 1u)) >> 16;
  return (unsigned short)u;
}
__device__ __forceinline__ float bf2f(unsigned short h) {
  return __uint_as_float((unsigned int)h << 16);
}
#define MFMA16(a, b, c) __builtin_amdgcn_mfma_f32_16x16x32_bf16((a), (b), (c), 0, 0, 0)

// ---------------- P1: per-block segment histogram ----------------
__global__ __launch_bounds__(256) void hist_k(
    const int* __restrict__ he_node, const int* __restrict__ he_edge,
    int* __restrict__ hist_t)        // [NSEG][NB_H]
{
  __shared__ int h[NSEG];
  const int tid = threadIdx.x;
  if (tid < NSEG) h[tid] = 0;
  __syncthreads();
  const int base = blockIdx.x * 1024;
  #pragma unroll
  for (int t = 0; t < 4; ++t) {
    const int e = base + t * 256 + tid;
    const int seg = he_node[e] * 2 + (he_edge[e] >= NUM_CLS);
    atomicAdd(&h[seg], 1);
  }
  __syncthreads();
  if (tid < NSEG) hist_t[tid * NB_H + blockIdx.x] = h[tid];
}

// ---------------- P2a: per-seg exclusive scan over blocks ----------------
__global__ __launch_bounds__(512) void scan_blocks_k(
    const int* __restrict__ hist_t, int* __restrict__ scan_t,
    int* __restrict__ seg_total)
{
  __shared__ int v[NB_H];
  const int s = blockIdx.x, tid = threadIdx.x;
  const int x0 = hist_t[s * NB_H + tid];
  v[tid] = x0;
  __syncthreads();
  for (int off = 1; off < NB_H; off <<= 1) {
    int y = (tid >= off) ? v[tid - off] : 0;
    __syncthreads();
    v[tid] += y;
    __syncthreads();
  }
  scan_t[s * NB_H + tid] = v[tid] - x0;     // exclusive
  if (tid == NB_H - 1) seg_total[s] = v[tid];
}

// ---------------- P2b: segment bases ----------------
__global__ __launch_bounds__(256) void base_k(
    const int* __restrict__ seg_total, int* __restrict__ seg_base,
    float* __restrict__ cnt_f)
{
  __shared__ int tot[NSEG];
  __shared__ int bs[NSEG + 1];
  const int tid = threadIdx.x;
  if (tid < NSEG) tot[tid] = seg_total[tid];
  __syncthreads();
  if (tid == 0) {
    int run = 0;
    for (int s = 0; s < NSEG; ++s) { bs[s] = run; run += tot[s]; }
    bs[NSEG] = run;
  }
  __syncthreads();
  if (tid < NSEG) { seg_base[tid] = bs[tid]; cnt_f[tid] = (float)tot[tid]; }
  if (tid == NSEG) seg_base[NSEG] = bs[NSEG];
}

// ---------------- P3: scatter row-offsets into seg-sorted order ----------------
__global__ __launch_bounds__(256) void scatter_k(
    const int* __restrict__ he_node, const int* __restrict__ he_edge,
    const int* __restrict__ scan_t, const int* __restrict__ seg_base,
    int* __restrict__ sorted_off)
{
  __shared__ int rank[NSEG];
  __shared__ int base[NSEG];
  const int tid = threadIdx.x;
  if (tid < NSEG) {
    rank[tid] = 0;
    base[tid] = seg_base[tid] + scan_t[tid * NB_H + blockIdx.x];
  }
  __syncthreads();
  const int e0 = blockIdx.x * 1024;
  #pragma unroll
  for (int t = 0; t < 4; ++t) {
    const int e = e0 + t * 256 + tid;
    const int node = he_node[e];
    const int edge = he_edge[e];
    const int isdc = (edge >= NUM_CLS);
    const int seg  = node * 2 + isdc;
    const int off  = (isdc ? edge - NUM_CLS : edge) * ROWLEN;
    const int r = atomicAdd(&rank[seg], 1);
    sorted_off[base[seg] + r] = off;
  }
}

// ---------------- P4: wave-per-entry accumulate; lane l owns cols l, 64+l ----
__global__ __launch_bounds__(256) void seg_acc_k(
    const float* __restrict__ dth_cls, const float* __restrict__ dth_dc,
    const int* __restrict__ sorted_off, const int* __restrict__ seg_base,
    float* __restrict__ partial)     // [NSEG][NCHUNK][ROWLEN]
{
  const int s = blockIdx.x;
  const int wid = threadIdx.x >> 6, lane = threadIdx.x & 63;
  const int chunk = blockIdx.y * 4 + wid;
  const int b0 = seg_base[s];
  const int n  = seg_base[s + 1] - b0;
  const int c0 = b0 + (int)(((long long)n * chunk) >> 5);
  const int c1 = b0 + (int)(((long long)n * (chunk + 1)) >> 5);
  const float* __restrict__ T = (s & 1) ? dth_dc : dth_cls;
  const bool tail = (lane < ROWLEN - 64);

  float accm = 0.f, acct = 0.f;
  int i = c0;
  for (; i + 4 <= c1; i += 4) {          // 4 rows in flight, coalesced 256B each
    const int o0 = sorted_off[i + 0];
    const int o1 = sorted_off[i + 1];
    const int o2 = sorted_off[i + 2];
    const int o3 = sorted_off[i + 3];
    const float v0 = T[o0 + lane];
    const float v1 = T[o1 + lane];
    const float v2 = T[o2 + lane];
    const float v3 = T[o3 + lane];
    float t0 = 0.f, t1 = 0.f, t2 = 0.f, t3 = 0.f;
    if (tail) {
      t0 = T[o0 + 64 + lane]; t1 = T[o1 + 64 + lane];
      t2 = T[o2 + 64 + lane]; t3 = T[o3 + 64 + lane];
    }
    accm += v0 + v1 + v2 + v3;
    acct += t0 + t1 + t2 + t3;
  }
  for (; i < c1; ++i) {
    const int o = sorted_off[i];
    accm += T[o + lane];
    if (tail) acct += T[o + 64 + lane];
  }

  float* dst = partial + ((size_t)s * NCHUNK + chunk) * ROWLEN;
  dst[lane] = accm;
  if (tail) dst[64 + lane] = acct;
}

// ---------------- P5+K3a fused: rowsum reduce + edge_group GEMV ----------------
__global__ __launch_bounds__(128) void seg_fin_edge_k(
    const float* __restrict__ partial, const float* __restrict__ cnt,
    const float* __restrict__ dE, const float* __restrict__ cE,
    float* __restrict__ edge_group)
{
  __shared__ float rs[ROWLEN];
  const int s = blockIdx.x, c = threadIdx.x;
  if (c < ROWLEN) {
    float v = 0.f;
    const float* p = partial + (size_t)s * NCHUNK * ROWLEN + c;
    #pragma unroll 8
    for (int k = 0; k < NCHUNK; ++k) v += p[k * ROWLEN];
    rs[c] = v;
  }
  __syncthreads();
  float a = 0.f;
  #pragma unroll
  for (int k = 0; k < DRUG_NUM; ++k) a += rs[k] * dE[k * FEA + c];
  #pragma unroll
  for (int k = DRUG_NUM; k < NUM_NODE; ++k) a += rs[k] * cE[(k - DRUG_NUM) * FEA + c];
  edge_group[s * FEA + c] = a / fmaxf(cnt[s], 1.f);
}

// ---------------- K3b: fc / projections / head-softmax / node_rep ----------------
__global__ __launch_bounds__(128) void node_rep_k(
    const float* __restrict__ edge_group, const float* __restrict__ dE,
    const float* __restrict__ cE, const float* __restrict__ node_proj,
    const float* __restrict__ edge_proj, const float* __restrict__ fc_w,
    const float* __restrict__ fc_b, float* __restrict__ node_rep)
{
  __shared__ float fw[FEA][FEA + 1];
  __shared__ float eg[2][FEA];
  __shared__ float mg[FEA];
  __shared__ float nm[FEA];
  __shared__ float em[2][FEA];
  __shared__ float ef[2][FEA];
  __shared__ float sc[4][2];
  __shared__ float wgt[4][2];

  const int n = blockIdx.x, c = threadIdx.x;
  const int isdrug = (n < DRUG_NUM);
  eg[0][c] = edge_group[(n * 2 + 0) * FEA + c];
  eg[1][c] = edge_group[(n * 2 + 1) * FEA + c];
  mg[c] = isdrug ? dE[n * FEA + c] : cE[(n - DRUG_NUM) * FEA + c];
  for (int r = 0; r < FEA; ++r) fw[r][c] = fc_w[r * FEA + c];
  __syncthreads();

  for (int e = 0; e < 2; ++e) {
    float a = fc_b[c];
    #pragma unroll 8
    for (int k = 0; k < FEA; ++k) a += eg[e][k] * fw[c][k];
    ef[e][c] = fmaxf(a, 0.f);
  }
  {
    const float* P = node_proj + (size_t)(isdrug ? 0 : 1) * FEA * FEA;
    float a = 0.f;
    #pragma unroll 8
    for (int k = 0; k < FEA; ++k) a += mg[k] * P[k * FEA + c];
    nm[c] = a;
  }
  for (int e = 0; e < 2; ++e) {
    const float* P = edge_proj + (size_t)((isdrug ? 0 : 2) + e) * FEA * FEA;
    float a = 0.f;
    #pragma unroll 8
    for (int k = 0; k < FEA; ++k) a += eg[e][k] * P[k * FEA + c];
    em[e][c] = a;
  }
  __syncthreads();

  if (c < 8) {
    const int h = c >> 1, e = c & 1;
    float s = 0.f;
    #pragma unroll
    for (int d = 0; d < 32; ++d) s += nm[h * 32 + d] * em[e][h * 32 + d];
    sc[h][e] = s * 0.17677669529663687f;
  }
  __syncthreads();
  if (c < 2) {
    const int e = c;
    const float mx = fmaxf(fmaxf(sc[0][e], sc[1][e]), fmaxf(sc[2][e], sc[3][e]));
    const float t0 = expf(sc[0][e] - mx), t1 = expf(sc[1][e] - mx);
    const float t2 = expf(sc[2][e] - mx), t3 = expf(sc[3][e] - mx);
    const float inv = 1.f / (t0 + t1 + t2 + t3);
    wgt[0][e] = t0 * inv; wgt[1][e] = t1 * inv;
    wgt[2][e] = t2 * inv; wgt[3][e] = t3 * inv;
  }
  __syncthreads();

  const int h = c >> 5;
  const float v = fmaxf(wgt[h][0] * ef[0][c], 0.f) + fmaxf(wgt[h][1] * ef[1][c], 0.f);
  node_rep[n * FEA + c] = v;
}

// ---------------- cvt: fp32 -> bf16 hi/lo split (RTNE) ----------------
__global__ __launch_bounds__(256) void cvt_split_k(
    const float* __restrict__ src, unsigned short* __restrict__ hi,
    unsigned short* __restrict__ lo, int n)
{
  const int i = blockIdx.x * 256 + threadIdx.x;
  if (i < n) {
    const float v = src[i];
    const unsigned short h = f2bf_rtne(v);
    hi[i] = h;
    lo[i] = f2bf_rtne(v - bf2f(h));
  }
}

// ---------------- K4a: BN'd node_rep per decoder part -> nodeBN[3][70][128] ----
__global__ __launch_bounds__(128) void nodebn_k(
    const float* __restrict__ node_rep,
    const float* __restrict__ gam, const float* __restrict__ bet,
    const float* __restrict__ mean, const float* __restrict__ var,
    unsigned short* __restrict__ nb_hi, unsigned short* __restrict__ nb_lo)
{
  const int n = blockIdx.x, p = blockIdx.y, c = threadIdx.x;
  const int j = p * FEA + c;
  float v = node_rep[n * FEA + c];
  v = (v - mean[j]) * rsqrtf(var[j] + 1e-5f) * gam[j] + bet[j];
  const int o = (p * NUM_NODE + n) * FEA + c;
  const unsigned short h = f2bf_rtne(v);
  nb_hi[o] = h;
  nb_lo[o] = f2bf_rtne(v - bf2f(h));
}

// ---------------- K4b: h1 = lrelu(emb @ w1^T + b1), split-bf16 MFMA ----
__global__ __launch_bounds__(256) void lin1_k(
    const unsigned short* __restrict__ nb_hi, const unsigned short* __restrict__ nb_lo,
    const int* __restrict__ index,
    const unsigned short* __restrict__ w_hi, const unsigned short* __restrict__ w_lo,
    const float* __restrict__ bias,
    unsigned short* __restrict__ h_hi, unsigned short* __restrict__ h_lo)
{
  const int lane = threadIdx.x & 63, wave = threadIdx.x >> 6;
  const int r16 = lane & 15, g = lane >> 4;
  const int wr = wave >> 1, wc = wave & 1;
  const int rowbase = blockIdx.y * 128 + wr * 64;
  const int colbase = blockIdx.x * 64 + wc * 32;

  int idx[4][3];
  #pragma unroll
  for (int t = 0; t < 4; ++t) {
    const int r = rowbase + t * 16 + r16;
    idx[t][0] = index[r * 3 + 0];
    idx[t][1] = index[r * 3 + 1];
    idx[t][2] = index[r * 3 + 2];
  }

  f32x4 acc[4][2];
  #pragma unroll
  for (int t = 0; t < 4; ++t) {
    acc[t][0] = (f32x4){0.f, 0.f, 0.f, 0.f};
    acc[t][1] = (f32x4){0.f, 0.f, 0.f, 0.f};
  }

  const size_t wrow0 = (size_t)(colbase + r16) * 384 + g * 8;
  const size_t wrow1 = (size_t)(colbase + 16 + r16) * 384 + g * 8;

  #pragma unroll
  for (int p = 0; p < 3; ++p) {
    #pragma unroll
    for (int q = 0; q < 4; ++q) {
      const int k0 = p * 128 + q * 32;
      bfrag ah[4], al[4];
      #pragma unroll
      for (int t = 0; t < 4; ++t) {
        const int abase = (p * NUM_NODE + idx[t][p]) * FEA + q * 32 + g * 8;
        ah[t] = *(const bfrag*)(nb_hi + abase);
        al[t] = *(const bfrag*)(nb_lo + abase);
      }
      const bfrag bh0 = *(const bfrag*)(w_hi + wrow0 + k0);
      const bfrag bh1 = *(const bfrag*)(w_hi + wrow1 + k0);
      const bfrag bl0 = *(const bfrag*)(w_lo + wrow0 + k0);
      const bfrag bl1 = *(const bfrag*)(w_lo + wrow1 + k0);
      #pragma unroll
      for (int t = 0; t < 4; ++t) {
        acc[t][0] = MFMA16(ah[t], bh0, acc[t][0]);
        acc[t][0] = MFMA16(ah[t], bl0, acc[t][0]);
        acc[t][0] = MFMA16(al[t], bh0, acc[t][0]);
        acc[t][1] = MFMA16(ah[t], bh1, acc[t][1]);
        acc[t][1] = MFMA16(ah[t], bl1, acc[t][1]);
        acc[t][1] = MFMA16(al[t], bh1, acc[t][1]);
      }
    }
  }

  #pragma unroll
  for (int t = 0; t < 4; ++t) {
    #pragma unroll
    for (int u = 0; u < 2; ++u) {
      const int col = colbase + u * 16 + r16;
      const float bv = bias[col];
      #pragma unroll
      for (int i = 0; i < 4; ++i) {
        float v = acc[t][u][i] + bv;
        v = v > 0.f ? v : 0.5f * v;
        const size_t o = (size_t)(rowbase + t * 16 + g * 4 + i) * 512 + col;
        const unsigned short h = f2bf_rtne(v);
        h_hi[o] = h;
        h_lo[o] = f2bf_rtne(v - bf2f(h));
      }
    }
  }
}

// ---------------- K4c: hout = lrelu(h1 @ w2^T + b2), fp32 out ----------------
__global__ __launch_bounds__(512) void lin2_k(
    const unsigned short* __restrict__ a_hi, const unsigned short* __restrict__ a_lo,
    const unsigned short* __restrict__ w_hi, const unsigned short* __restrict__ w_lo,
    const float* __restrict__ bias, float* __restrict__ C)
{
  const int lane = threadIdx.x & 63, wave = threadIdx.x >> 6;
  const int r16 = lane & 15, g = lane >> 4;
  const int wr = wave >> 1, wc = wave & 1;
  const int rowbase = blockIdx.y * 128 + wr * 32;
  const int colbase = blockIdx.x * 64 + wc * 32;

  const size_t arow0 = (size_t)(rowbase + r16) * 512 + g * 8;
  const size_t arow1 = (size_t)(rowbase + 16 + r16) * 512 + g * 8;
  const size_t wrow0 = (size_t)(colbase + r16) * 512 + g * 8;
  const size_t wrow1 = (size_t)(colbase + 16 + r16) * 512 + g * 8;

  f32x4 acc00 = {0.f, 0.f, 0.f, 0.f}, acc01 = acc00, acc10 = acc00, acc11 = acc00;

  #pragma unroll 4
  for (int k0 = 0; k0 < 512; k0 += 32) {
    const bfrag ah0 = *(const bfrag*)(a_hi + arow0 + k0);
    const bfrag ah1 = *(const bfrag*)(a_hi + arow1 + k0);
    const bfrag al0 = *(const bfrag*)(a_lo + arow0 + k0);
    const bfrag al1 = *(const bfrag*)(a_lo + arow1 + k0);
    const bfrag bh0 = *(const bfrag*)(w_hi + wrow0 + k0);
    const bfrag bh1 = *(const bfrag*)(w_hi + wrow1 + k0);
    const bfrag bl0 = *(const bfrag*)(w_lo + wrow0 + k0);
    const bfrag bl1 = *(const bfrag*)(w_lo + wrow1 + k0);
    acc00 = MFMA16(ah0, bh0, acc00); acc00 = MFMA16(ah0, bl0, acc00); acc00 = MFMA16(al0, bh0, acc00);
    acc01 = MFMA16(ah0, bh1, acc01); acc01 = MFMA16(ah0, bl1, acc01); acc01 = MFMA16(al0, bh1, acc01);
    acc10 = MFMA16(ah1, bh0, acc10); acc10 = MFMA16(ah1, bl0, acc10); acc10 = MFMA16(al1, bh0, acc10);
    acc11 = MFMA16(ah1, bh1, acc11); acc11 = MFMA16(ah1, bl1, acc11); acc11 = MFMA16(al1, bh1, acc11);
  }

  f32x4 av[2][2] = {{acc00, acc01}, {acc10, acc11}};
  #pragma unroll
  for (int t = 0; t < 2; ++t) {
    #pragma unroll
    for (int u = 0; u < 2; ++u) {
      const int col = colbase + u * 16 + r16;
      const float bv = bias[col];
      #pragma unroll
      for (int i = 0; i < 4; ++i) {
        float v = av[t][u][i] + bv;
        v = v > 0.f ? v : 0.5f * v;
        C[(size_t)(rowbase + t * 16 + g * 4 + i) * 256 + col] = v;
      }
    }
  }
}

// ---------------- K4d: out0 = sigmoid(h @ w3 + b3) ----------------
__global__ __launch_bounds__(256) void lin3_k(
    const float* __restrict__ H, const float* __restrict__ w3,
    const float* __restrict__ b3, float* __restrict__ out)
{
  const int row = blockIdx.x * 4 + (threadIdx.x >> 6);
  const int lane = threadIdx.x & 63;
  const float4 h = *(const float4*)(H + (size_t)row * 256 + lane * 4);
  const float4 w = *(const float4*)(w3 + lane * 4);
  float v = h.x * w.x + h.y * w.y + h.z * w.z + h.w * w.w;
  #pragma unroll
  for (int off = 32; off; off >>= 1) v += __shfl_down(v, off);
  if (lane == 0) out[row] = 1.f / (1.f + expf(-(v + b3[0])));
}

extern "C" void kernel_launch(void* const* d_in, const int* in_sizes, int n_in,
                              void* d_out, int out_size, void* d_ws, size_t ws_size,
                              hipStream_t stream) {
  const float* dth_cls  = (const float*)d_in[2];
  const float* dth_dc   = (const float*)d_in[3];
  const int*   he_node  = (const int*)d_in[4];
  const int*   he_edge  = (const int*)d_in[5];
  const int*   index    = (const int*)d_in[7];
  const float* dE       = (const float*)d_in[8];
  const float* cE       = (const float*)d_in[9];
  const float* node_proj= (const float*)d_in[10];
  const float* edge_proj= (const float*)d_in[11];
  const float* fc_w     = (const float*)d_in[12];
  const float* fc_b     = (const float*)d_in[13];
  const float* bn_g     = (const float*)d_in[14];
  const float* bn_b     = (const float*)d_in[15];
  const float* bn_m     = (const float*)d_in[16];
  const float* bn_v     = (const float*)d_in[17];
  const float* w1       = (const float*)d_in[18];
  const float* b1       = (const float*)d_in[19];
  const float* w2       = (const float*)d_in[20];
  const float* b2       = (const float*)d_in[21];
  const float* w3       = (const float*)d_in[22];
  const float* b3       = (const float*)d_in[23];

  float* out0 = (float*)d_out;
  float* hout = out0 + BATCH;                      // [8192,256] fp32, 2nd output

  float* ws = (float*)d_ws;
  float*          rowsum    = ws + 0;                          // (unused slot kept)
  float*          cnt_f     = ws + 9856;                       // -> 9996
  float*          edge_group= ws + 10048;                      // -> 27968
  float*          node_rep  = ws + 28032;                      // -> 36992
  unsigned short* nb_hi     = (unsigned short*)(ws + 37056);   // 26880 bf16
  unsigned short* nb_lo     = (unsigned short*)(ws + 50560);   // 26880 bf16
  unsigned short* w1_hi     = (unsigned short*)(ws + 64000);   // 196608 bf16
  unsigned short* w1_lo     = (unsigned short*)(ws + 162304);
  unsigned short* w2_hi     = (unsigned short*)(ws + 260608);  // 131072 bf16
  unsigned short* w2_lo     = (unsigned short*)(ws + 326144);
  unsigned short* h1_hi     = (unsigned short*)(ws + 391744);  // 8192*512 bf16 -> +2097152 fl
  unsigned short* h1_lo     = (unsigned short*)(ws + 2488960); // -> end 4586112 fl (18.3 MB)
  // seg scratch aliased into h1 span (fully consumed before lin1 writes h1):
  int*            sorted_off= (int*)(ws + 391744);             // 524288 -> 916032
  int*            hist_t    = (int*)(ws + 916032);             // 71680
  int*            scan_t    = (int*)(ws + 987712);             // 71680
  int*            seg_total = (int*)(ws + 1059392);            // 140
  int*            seg_base  = (int*)(ws + 1059532);            // 141
  float*          partial   = ws + 1059680;                    // 313600 -> 1373280
  (void)rowsum;

  // weight split conversions (independent of everything else)
  cvt_split_k<<<(512 * 384 + 255) / 256, 256, 0, stream>>>(w1, w1_hi, w1_lo, 512 * 384);
  cvt_split_k<<<(256 * 512 + 255) / 256, 256, 0, stream>>>(w2, w2_hi, w2_lo, 256 * 512);

  // segment-mean pipeline
  hist_k<<<NB_H, 256, 0, stream>>>(he_node, he_edge, hist_t);
  scan_blocks_k<<<NSEG, NB_H, 0, stream>>>(hist_t, scan_t, seg_total);
  base_k<<<1, 256, 0, stream>>>(seg_total, seg_base, cnt_f);
  scatter_k<<<NB_H, 256, 0, stream>>>(he_node, he_edge, scan_t, seg_base, sorted_off);
  seg_acc_k<<<dim3(NSEG, NCHUNK / 4), 256, 0, stream>>>(dth_cls, dth_dc, sorted_off,
                                                        seg_base, partial);
  seg_fin_edge_k<<<NSEG, 128, 0, stream>>>(partial, cnt_f, dE, cE, edge_group);
  node_rep_k<<<NUM_NODE, 128, 0, stream>>>(edge_group, dE, cE, node_proj, edge_proj,
                                           fc_w, fc_b, node_rep);

  // decoder: split-bf16 MFMA, emb gathered on the fly
  nodebn_k<<<dim3(NUM_NODE, 3), 128, 0, stream>>>(node_rep, bn_g, bn_b, bn_m, bn_v,
                                                  nb_hi, nb_lo);
  lin1_k<<<dim3(512 / 64, BATCH / 128), 256, 0, stream>>>(nb_hi, nb_lo, index,
                                                          w1_hi, w1_lo, b1, h1_hi, h1_lo);
  lin2_k<<<dim3(256 / 64, BATCH / 128), 512, 0, stream>>>(h1_hi, h1_lo, w2_hi, w2_lo,
                                                          b2, hout);
  lin3_k<<<BATCH / 4, 256, 0, stream>>>(hout, w3, b3, out0);
}